// Round 2
// baseline (2943.333 us; speedup 1.0000x reference)
//
#include <hip/hip_runtime.h>
#include <hip/hip_cooperative_groups.h>

namespace cg = cooperative_groups;

#define STYLE_EPS 1e-4f

typedef __bf16 bf16x8 __attribute__((ext_vector_type(8)));
typedef float f32x4 __attribute__((ext_vector_type(4)));

// ---------------------------------------------------------------- reductions
__device__ __forceinline__ float block_reduce_sum(float v) {
  __shared__ float ws[8];
  #pragma unroll
  for (int off = 32; off > 0; off >>= 1) v += __shfl_down(v, off, 64);
  __syncthreads();                       // protect ws across repeated calls
  int lane = threadIdx.x & 63, wid = threadIdx.x >> 6;
  if (lane == 0) ws[wid] = v;
  __syncthreads();
  float s = 0.f;
  int nw = (blockDim.x + 63) >> 6;
  for (int i = 0; i < nw; ++i) s += ws[i];
  return s;
}

// ------------------------------------------------- split-bf16 MFMA Gram
// srm[b] += X_tile_i @ X_tile_j^T, 3-term bf16 split (HH^T + HL^T + LH^T).
// Also accumulates per-row sums (for the mean) from the diagonal-pair A-loads,
// where every element is loaded exactly once across the grid.
// grid: (32 chunks, 3 tile-pairs {(0,0),(0,1),(1,1)}, 9 mats: z=0..7 batch, z=8 target)

__device__ __forceinline__ uint pack2hi(uint u0, uint u1) {
  // u32 = (bf16(u1) << 16) | bf16(u0)   (truncating round)
  return __builtin_amdgcn_perm(u1, u0, 0x07060302u);
}

__device__ __forceinline__ void cvt_span(float4 v0, float4 v1, uint4& h, uint4& l) {
  uint b0 = __float_as_uint(v0.x), b1 = __float_as_uint(v0.y);
  uint b2 = __float_as_uint(v0.z), b3 = __float_as_uint(v0.w);
  uint b4 = __float_as_uint(v1.x), b5 = __float_as_uint(v1.y);
  uint b6 = __float_as_uint(v1.z), b7 = __float_as_uint(v1.w);
  h.x = pack2hi(b0, b1); h.y = pack2hi(b2, b3);
  h.z = pack2hi(b4, b5); h.w = pack2hi(b6, b7);
  float l0 = v0.x - __uint_as_float(b0 & 0xFFFF0000u);
  float l1 = v0.y - __uint_as_float(b1 & 0xFFFF0000u);
  float l2 = v0.z - __uint_as_float(b2 & 0xFFFF0000u);
  float l3 = v0.w - __uint_as_float(b3 & 0xFFFF0000u);
  float l4 = v1.x - __uint_as_float(b4 & 0xFFFF0000u);
  float l5 = v1.y - __uint_as_float(b5 & 0xFFFF0000u);
  float l6 = v1.z - __uint_as_float(b6 & 0xFFFF0000u);
  float l7 = v1.w - __uint_as_float(b7 & 0xFFFF0000u);
  l.x = pack2hi(__float_as_uint(l0), __float_as_uint(l1));
  l.y = pack2hi(__float_as_uint(l2), __float_as_uint(l3));
  l.z = pack2hi(__float_as_uint(l4), __float_as_uint(l5));
  l.w = pack2hi(__float_as_uint(l6), __float_as_uint(l7));
}

__global__ __launch_bounds__(256, 2)
void gram_mfma_kernel(const float* __restrict__ X, const float* __restrict__ TF,
                      float* __restrict__ srmB, float* __restrict__ srmT,
                      float* __restrict__ msumB, float* __restrict__ msumT) {
  __shared__ __align__(16) char ldsAh[16384];
  __shared__ __align__(16) char ldsAl[16384];
  __shared__ __align__(16) char ldsBh[16384];
  __shared__ __align__(16) char ldsBl[16384];

  const int pair = blockIdx.y;
  const int ti = (pair == 2) ? 1 : 0;
  const int tj = (pair == 0) ? 0 : 1;
  const bool diag = (ti == tj);
  const int b = blockIdx.z;

  const float* Xb; float* srm; float* msum; int K, kchunk;
  if (b == 8) { Xb = TF; srm = srmT; msum = msumT; K = 16384; kchunk = 512; }
  else {
    Xb = X + (size_t)b * 256 * 65536;
    srm = srmB + ((size_t)b << 16);
    msum = msumB + (b << 8);
    K = 65536; kchunk = 2048;
  }
  const float* __restrict__ Ab = Xb + (size_t)(ti * 128) * (size_t)K;
  const float* __restrict__ Bb = Xb + (size_t)(tj * 128) * (size_t)K;
  const int k0 = blockIdx.x * kchunk;

  const int t = threadIdx.x;
  const int lane = t & 63, wid = t >> 6;
  const int wr = (wid >> 1) * 64;          // wave row base within 128-tile
  const int wc = (wid & 1) * 64;           // wave col base within 128-tile
  const int srow = t >> 3;                 // staging: base row 0..31
  const int sspan = t & 7;                 // staging: 8-elem span 0..7

  f32x4 acc[4][4];
  #pragma unroll
  for (int m = 0; m < 4; ++m)
    #pragma unroll
    for (int n = 0; n < 4; ++n) acc[m][n] = (f32x4){0.f, 0.f, 0.f, 0.f};

  float rsum[4] = {0.f, 0.f, 0.f, 0.f};

  const float* pA = Ab + (size_t)srow * K + k0 + sspan * 8;
  const float* pB = Bb + (size_t)srow * K + k0 + sspan * 8;

  for (int kk = 0; kk < kchunk; kk += 64) {
    float4 ra[8], rb[8];
    #pragma unroll
    for (int rep = 0; rep < 4; ++rep) {
      const float* p = pA + (size_t)(rep * 32) * K + kk;
      ra[2 * rep]     = *(const float4*)(p);
      ra[2 * rep + 1] = *(const float4*)(p + 4);
    }
    if (!diag) {
      #pragma unroll
      for (int rep = 0; rep < 4; ++rep) {
        const float* p = pB + (size_t)(rep * 32) * K + kk;
        rb[2 * rep]     = *(const float4*)(p);
        rb[2 * rep + 1] = *(const float4*)(p + 4);
      }
    } else {
      #pragma unroll
      for (int rep = 0; rep < 4; ++rep) {
        float4 u0 = ra[2 * rep], u1 = ra[2 * rep + 1];
        rsum[rep] += (u0.x + u0.y) + (u0.z + u0.w) + (u1.x + u1.y) + (u1.z + u1.w);
      }
    }
    __syncthreads();   // prev compute done -> safe to overwrite LDS
    #pragma unroll
    for (int rep = 0; rep < 4; ++rep) {
      int r = srow + rep * 32;
      int off = (r << 7) + ((sspan << 4) ^ ((r & 7) << 4));
      uint4 h, l;
      cvt_span(ra[2 * rep], ra[2 * rep + 1], h, l);
      *(uint4*)(ldsAh + off) = h;
      *(uint4*)(ldsAl + off) = l;
      if (!diag) {
        cvt_span(rb[2 * rep], rb[2 * rep + 1], h, l);
        *(uint4*)(ldsBh + off) = h;
        *(uint4*)(ldsBl + off) = l;
      }
    }
    __syncthreads();
    const char* BH = diag ? ldsAh : ldsBh;
    const char* BL = diag ? ldsAl : ldsBl;
    #pragma unroll
    for (int ks = 0; ks < 2; ++ks) {
      const int kb = ks * 64 + ((lane >> 4) << 4);
      bf16x8 ah[4], al[4];
      #pragma unroll
      for (int m = 0; m < 4; ++m) {
        int r = wr + m * 16 + (lane & 15);
        int o = (r << 7) + (kb ^ ((r & 7) << 4));
        ah[m] = *(const bf16x8*)(ldsAh + o);
        al[m] = *(const bf16x8*)(ldsAl + o);
      }
      #pragma unroll
      for (int n = 0; n < 4; ++n) {
        int r = wc + n * 16 + (lane & 15);
        int o = (r << 7) + (kb ^ ((r & 7) << 4));
        bf16x8 bh = *(const bf16x8*)(BH + o);
        bf16x8 bl = *(const bf16x8*)(BL + o);
        #pragma unroll
        for (int m = 0; m < 4; ++m) {
          acc[m][n] = __builtin_amdgcn_mfma_f32_16x16x32_bf16(ah[m], bh, acc[m][n], 0, 0, 0);
          acc[m][n] = __builtin_amdgcn_mfma_f32_16x16x32_bf16(ah[m], bl, acc[m][n], 0, 0, 0);
          acc[m][n] = __builtin_amdgcn_mfma_f32_16x16x32_bf16(al[m], bh, acc[m][n], 0, 0, 0);
        }
      }
    }
  }
  if (diag) {
    int rbase = ti * 128 + srow;
    #pragma unroll
    for (int rep = 0; rep < 4; ++rep)
      atomicAdd(msum + rbase + rep * 32, rsum[rep]);
  }
  // C/D layout col=lane&15, row=(lane>>4)*4+q (m89)
  const int rq = (lane >> 4) << 2;
  const int cl = lane & 15;
  #pragma unroll
  for (int m = 0; m < 4; ++m) {
    #pragma unroll
    for (int n = 0; n < 4; ++n) {
      #pragma unroll
      for (int q = 0; q < 4; ++q) {
        int r = ti * 128 + wr + m * 16 + rq + q;
        int c = tj * 128 + wc + n * 16 + cl;
        atomicAdd(srm + (size_t)r * 256 + c, acc[m][n][q]);
      }
    }
  }
}

// ------------------------------------------------- 256x256x256 fp32 gemm tiles
// 64x64 tile, 4x4 micro; returns sum of squares of outputs (frob fusion).
__device__ __forceinline__ float gemm64_tile(const float* __restrict__ A,
                                             const float* __restrict__ B,
                                             float* __restrict__ C,
                                             float alpha, float diag_add, int tile) {
  __shared__ float As[32][64];
  __shared__ float Bs[32][64];
  const int tm = tile >> 2, tn = tile & 3;
  const int t = threadIdx.x;
  const int tx = t & 15, ty = t >> 4;
  const int arow = t >> 2, akq = (t & 3) * 8;
  const int brow = t >> 3, bnq = (t & 7) * 8;
  float acc[4][4];
  #pragma unroll
  for (int i = 0; i < 4; ++i)
    #pragma unroll
    for (int j = 0; j < 4; ++j) acc[i][j] = 0.f;

  for (int kk = 0; kk < 256; kk += 32) {
    float4 a0 = *(const float4*)(A + (size_t)(tm * 64 + arow) * 256 + kk + akq);
    float4 a1 = *(const float4*)(A + (size_t)(tm * 64 + arow) * 256 + kk + akq + 4);
    float4 b0 = *(const float4*)(B + (size_t)(kk + brow) * 256 + tn * 64 + bnq);
    float4 b1 = *(const float4*)(B + (size_t)(kk + brow) * 256 + tn * 64 + bnq + 4);
    __syncthreads();
    As[akq + 0][arow] = a0.x; As[akq + 1][arow] = a0.y; As[akq + 2][arow] = a0.z; As[akq + 3][arow] = a0.w;
    As[akq + 4][arow] = a1.x; As[akq + 5][arow] = a1.y; As[akq + 6][arow] = a1.z; As[akq + 7][arow] = a1.w;
    *(float4*)&Bs[brow][bnq] = b0;
    *(float4*)&Bs[brow][bnq + 4] = b1;
    __syncthreads();
    #pragma unroll 8
    for (int k = 0; k < 32; ++k) {
      float4 av4 = *(const float4*)&As[k][ty * 4];
      float4 bv4 = *(const float4*)&Bs[k][tx * 4];
      float av[4] = {av4.x, av4.y, av4.z, av4.w};
      float bv[4] = {bv4.x, bv4.y, bv4.z, bv4.w};
      #pragma unroll
      for (int i = 0; i < 4; ++i)
        #pragma unroll
        for (int j = 0; j < 4; ++j)
          acc[i][j] = fmaf(av[i], bv[j], acc[i][j]);
    }
  }
  float fs = 0.f;
  #pragma unroll
  for (int i = 0; i < 4; ++i) {
    int r = tm * 64 + ty * 4 + i;
    #pragma unroll
    for (int j = 0; j < 4; ++j) {
      int c = tn * 64 + tx * 4 + j;
      float v = alpha * acc[i][j];
      if (r == c) v += diag_add;
      C[(size_t)r * 256 + c] = v;
      fs = fmaf(v, v, fs);
    }
  }
  return fs;
}

// 32x32 tile, 2x2 micro — higher parallelism for the (tiny) target-NS GEMMs.
__device__ __forceinline__ void gemm32_tile(const float* __restrict__ A,
                                            const float* __restrict__ B,
                                            float* __restrict__ C,
                                            float alpha, float diag_add, int tile) {
  __shared__ float As[32][32];
  __shared__ float Bs[32][32];
  const int tm = tile >> 3, tn = tile & 7;
  const int t = threadIdx.x;
  const int tx = t & 15, ty = t >> 4;      // 16x16 threads, 2x2 micro
  const int srow = t >> 3;                 // 0..31
  const int sc4 = (t & 7) << 2;            // 0..28 step 4
  float a00 = 0.f, a01 = 0.f, a10 = 0.f, a11 = 0.f;
  for (int kk = 0; kk < 256; kk += 32) {
    float4 a = *(const float4*)(A + (size_t)(tm * 32 + srow) * 256 + kk + sc4);
    float4 bq = *(const float4*)(B + (size_t)(kk + srow) * 256 + tn * 32 + sc4);
    __syncthreads();
    As[sc4 + 0][srow] = a.x; As[sc4 + 1][srow] = a.y;
    As[sc4 + 2][srow] = a.z; As[sc4 + 3][srow] = a.w;
    *(float4*)&Bs[srow][sc4] = bq;
    __syncthreads();
    #pragma unroll
    for (int k = 0; k < 32; ++k) {
      float2 av = *(const float2*)&As[k][ty * 2];
      float2 bv = *(const float2*)&Bs[k][tx * 2];
      a00 = fmaf(av.x, bv.x, a00); a01 = fmaf(av.x, bv.y, a01);
      a10 = fmaf(av.y, bv.x, a10); a11 = fmaf(av.y, bv.y, a11);
    }
  }
  int r0 = tm * 32 + ty * 2, c0 = tn * 32 + tx * 2;
  float v;
  v = alpha * a00; if (r0 == c0) v += diag_add;         C[(size_t)r0 * 256 + c0] = v;
  v = alpha * a01;                                      C[(size_t)r0 * 256 + c0 + 1] = v;
  v = alpha * a10;                                      C[(size_t)(r0 + 1) * 256 + c0] = v;
  v = alpha * a11; if (r0 + 1 == c0 + 1) v += diag_add; C[(size_t)(r0 + 1) * 256 + c0 + 1] = v;
}

// ------------------------------------------------- target NS chain (coop, 128 blocks)
// cov finalize + frob -> init -> 12 NS iters -> covSqrt
__global__ __launch_bounds__(256)
void ns_coop_target(const float* __restrict__ srm, const float* __restrict__ msum,
                    float* __restrict__ cov, float* __restrict__ covSqrt,
                    float* __restrict__ Ybuf, float* __restrict__ Zbuf,
                    float* __restrict__ Ynb, float* __restrict__ Znb,
                    float* __restrict__ Tbuf, float* __restrict__ ssq) {
  cg::grid_group g = cg::this_grid();
  const int bid = blockIdx.x, tid = threadIdx.x;
  const int gt = bid * 256 + tid;             // 0..32767
  const float inv_n = 1.f / 16384.f;
  // phase 0: cov (with (1,0)-tile mirror) + Frobenius
  float fs = 0.f;
  for (int i = gt; i < 65536; i += 32768) {
    int c = i >> 8, d = i & 255;
    float s = ((c >> 7) > (d >> 7)) ? srm[(d << 8) + c] : srm[i];
    float v = s * inv_n - (msum[c] * inv_n) * (msum[d] * inv_n);
    if (c == d) v += STYLE_EPS;
    cov[i] = v;
    fs = fmaf(v, v, fs);
  }
  fs = block_reduce_sum(fs);
  if (tid == 0) atomicAdd(ssq, fs);
  g.sync();
  // phase 1: Y = cov * rsqrt(||cov||^2), Z = I
  float rn = rsqrtf(ssq[0]);
  for (int i = gt; i < 65536; i += 32768) {
    Ybuf[i] = cov[i] * rn;
    Zbuf[i] = ((i >> 8) == (i & 255)) ? 1.f : 0.f;
  }
  g.sync();
  float *y = Ybuf, *z = Zbuf, *yn = Ynb, *zn = Znb;
  for (int it = 0; it < 12; ++it) {
    if (bid < 64) gemm32_tile(z, y, Tbuf, -0.5f, 1.5f, bid);
    g.sync();
    if (bid < 64) gemm32_tile(y, Tbuf, yn, 1.f, 0.f, bid);
    else          gemm32_tile(Tbuf, z, zn, 1.f, 0.f, bid - 64);
    g.sync();
    float* tp;
    tp = y; y = yn; yn = tp;
    tp = z; z = zn; zn = tp;
  }
  float f = sqrtf(sqrtf(ssq[0]));
  for (int i = gt; i < 65536; i += 32768) covSqrt[i] = y[i] * f;
}

// ------------------------------------------------- batch chain (coop, 256 blocks)
// covB finalize -> sandwich (P1=covTs@covB, Mm=P1@covTs + frob) -> init ->
// 12 NS iters -> loss
__global__ __launch_bounds__(256)
void ns_coop_batch(const float* __restrict__ srm, const float* __restrict__ msumB,
                   const float* __restrict__ msumT,
                   const float* __restrict__ covTs, const float* __restrict__ covT,
                   float* __restrict__ covB, float* __restrict__ P1, float* __restrict__ Mm,
                   float* __restrict__ Ybuf, float* __restrict__ Zbuf,
                   float* __restrict__ Ynb, float* __restrict__ Znb,
                   float* __restrict__ Tbuf, float* __restrict__ ssq,
                   float* __restrict__ out) {
  cg::grid_group g = cg::this_grid();
  const int bid = blockIdx.x, tid = threadIdx.x;
  const int gt = bid * 256 + tid;              // 0..65535
  const float inv_n = 1.f / 65536.f;
  const size_t M = 65536;
  // phase 0: covB finalize (with mirror)
  for (int i = gt; i < 524288; i += 65536) {
    int m = i >> 16, r = i & 65535;
    int c = r >> 8, d = r & 255;
    size_t base = (size_t)m << 16;
    float s = ((c >> 7) > (d >> 7)) ? srm[base + ((size_t)d << 8) + c] : srm[i];
    float mc = msumB[(m << 8) + c] * inv_n, md = msumB[(m << 8) + d] * inv_n;
    float v = s * inv_n - mc * md;
    if (c == d) v += STYLE_EPS;
    covB[i] = v;
  }
  g.sync();
  // phase 1: P1 = covTs @ covB
  if (bid < 128) {
    int m = bid >> 4, tl = bid & 15;
    gemm64_tile(covTs, covB + m * M, P1 + m * M, 1.f, 0.f, tl);
  }
  g.sync();
  // phase 2: Mm = P1 @ covTs  (+ fused Frobenius per matrix)
  if (bid < 128) {
    int m = bid >> 4, tl = bid & 15;
    float fs = gemm64_tile(P1 + m * M, covTs, Mm + m * M, 1.f, 0.f, tl);
    fs = block_reduce_sum(fs);
    if (tid == 0) atomicAdd(ssq + m, fs);
  }
  g.sync();
  // phase 3: init
  for (int i = gt; i < 524288; i += 65536) {
    int m = i >> 16, r = i & 65535;
    Ybuf[i] = Mm[i] * rsqrtf(ssq[m]);
    Zbuf[i] = ((r >> 8) == (r & 255)) ? 1.f : 0.f;
  }
  g.sync();
  float *y = Ybuf, *z = Zbuf, *yn = Ynb, *zn = Znb;
  for (int it = 0; it < 12; ++it) {
    if (bid < 128) {
      int m = bid >> 4, tl = bid & 15;
      gemm64_tile(z + m * M, y + m * M, Tbuf + m * M, -0.5f, 1.5f, tl);
    }
    g.sync();
    if (bid < 128) {
      int m = bid >> 4, tl = bid & 15;
      gemm64_tile(y + m * M, Tbuf + m * M, yn + m * M, 1.f, 0.f, tl);
    } else {
      int m = (bid - 128) >> 4, tl = (bid - 128) & 15;
      gemm64_tile(Tbuf + m * M, z + m * M, zn + m * M, 1.f, 0.f, tl);
    }
    g.sync();
    float* tp;
    tp = y; y = yn; yn = tp;
    tp = z; z = zn; zn = tp;
  }
  // loss (block 0): diag of sqrt_term taken from y scaled on the fly
  if (bid == 0) {
    const float invT = 1.f / 16384.f;
    float s1 = 0.f, s2 = 0.f;
    for (int i = tid; i < 2048; i += 256) {
      int b = i >> 8, c = i & 255;
      float dm = msumB[i] * inv_n - msumT[c] * invT;
      s1 += dm * dm;
      size_t di = ((size_t)b << 16) + (size_t)c * 257;
      float fb = sqrtf(sqrtf(ssq[b]));
      s2 += covT[(size_t)c * 257] + covB[di] - 2.f * fb * y[di];
    }
    s1 = block_reduce_sum(s1);
    s2 = block_reduce_sum(s2);
    if (tid == 0) out[0] = (s1 + s2) / 2048.f;
  }
}

// ------------------------------------------------------------------- launch
extern "C" void kernel_launch(void* const* d_in, const int* in_sizes, int n_in,
                              void* d_out, int out_size, void* d_ws, size_t ws_size,
                              hipStream_t stream) {
  const float* x  = (const float*)d_in[0];   // [8,256,256,256]
  const float* tf = (const float*)d_in[1];   // [256,16384]
  float* out = (float*)d_out;
  float* W = (float*)d_ws;

  const size_t M = 65536;   // 256*256
  float* sumsq = W;                       // 16  (batch 0..7, target at 8)
  float* meanT = W + 16;                  // 256  (raw row sums)
  float* meanB = meanT + 256;             // 2048 (raw row sums)
  float* srmT  = meanB + 2048;            // 65536
  float* srmB  = srmT + M;                // 8*65536
  float* covT  = srmB + 8 * M;            // 65536
  float* covTs = covT + M;                // 65536
  float* covB  = covTs + M;               // 8*65536
  float* P1    = covB + 8 * M;            // 8*65536
  float* Mm    = P1 + 8 * M;              // 8*65536
  float* Ya    = Mm + 8 * M;              // 8*65536
  float* Yb    = Ya + 8 * M;
  float* Za    = Yb + 8 * M;
  float* Zb    = Za + 8 * M;
  float* Tm    = Zb + 8 * M;

  // zero atomic accumulators: sumsq + mean sums + srmT + srmB (contiguous)
  hipMemsetAsync(W, 0, (16 + 256 + 2048 + 9 * M) * sizeof(float), stream);

  // grams (z=0..7 batch mats, z=8 target) + fused row-sum accumulation
  gram_mfma_kernel<<<dim3(32, 3, 9), 256, 0, stream>>>(x, tf, srmB, srmT, meanB, meanT);

  // target chain: covT -> NS -> covTs
  {
    float* ssqT = sumsq + 8;
    void* args[] = {(void*)&srmT, (void*)&meanT, (void*)&covT, (void*)&covTs,
                    (void*)&Ya, (void*)&Za, (void*)&Yb, (void*)&Zb, (void*)&Tm,
                    (void*)&ssqT};
    hipLaunchCooperativeKernel((void*)ns_coop_target, dim3(128), dim3(256), args, 0, stream);
  }

  // batch chain: covB -> sandwich -> NS(8) -> loss
  {
    void* args[] = {(void*)&srmB, (void*)&meanB, (void*)&meanT, (void*)&covTs, (void*)&covT,
                    (void*)&covB, (void*)&P1, (void*)&Mm,
                    (void*)&Ya, (void*)&Za, (void*)&Yb, (void*)&Zb, (void*)&Tm,
                    (void*)&sumsq, (void*)&out};
    hipLaunchCooperativeKernel((void*)ns_coop_batch, dim3(256), dim3(256), args, 0, stream);
  }
}

// Round 3
// 2417.785 us; speedup vs baseline: 1.2174x; 1.2174x over previous
//
#include <hip/hip_runtime.h>
#include <hip/hip_cooperative_groups.h>

namespace cg = cooperative_groups;

#define STYLE_EPS 1e-4f

typedef __bf16 bf16x8 __attribute__((ext_vector_type(8)));
typedef float f32x4 __attribute__((ext_vector_type(4)));

// ---------------------------------------------------------------- reductions
__device__ __forceinline__ float block_reduce_sum(float v) {
  __shared__ float ws[8];
  #pragma unroll
  for (int off = 32; off > 0; off >>= 1) v += __shfl_down(v, off, 64);
  __syncthreads();                       // protect ws across repeated calls
  int lane = threadIdx.x & 63, wid = threadIdx.x >> 6;
  if (lane == 0) ws[wid] = v;
  __syncthreads();
  float s = 0.f;
  int nw = (blockDim.x + 63) >> 6;
  for (int i = 0; i < nw; ++i) s += ws[i];
  return s;
}

// ------------------------------------------------- split-bf16 helpers
__device__ __forceinline__ uint pack2hi(uint u0, uint u1) {
  // u32 = (bf16(u1) << 16) | bf16(u0)   (truncating round)
  return __builtin_amdgcn_perm(u1, u0, 0x07060302u);
}

__device__ __forceinline__ void cvt_span(float4 v0, float4 v1, uint4& h, uint4& l) {
  uint b0 = __float_as_uint(v0.x), b1 = __float_as_uint(v0.y);
  uint b2 = __float_as_uint(v0.z), b3 = __float_as_uint(v0.w);
  uint b4 = __float_as_uint(v1.x), b5 = __float_as_uint(v1.y);
  uint b6 = __float_as_uint(v1.z), b7 = __float_as_uint(v1.w);
  h.x = pack2hi(b0, b1); h.y = pack2hi(b2, b3);
  h.z = pack2hi(b4, b5); h.w = pack2hi(b6, b7);
  float l0 = v0.x - __uint_as_float(b0 & 0xFFFF0000u);
  float l1 = v0.y - __uint_as_float(b1 & 0xFFFF0000u);
  float l2 = v0.z - __uint_as_float(b2 & 0xFFFF0000u);
  float l3 = v0.w - __uint_as_float(b3 & 0xFFFF0000u);
  float l4 = v1.x - __uint_as_float(b4 & 0xFFFF0000u);
  float l5 = v1.y - __uint_as_float(b5 & 0xFFFF0000u);
  float l6 = v1.z - __uint_as_float(b6 & 0xFFFF0000u);
  float l7 = v1.w - __uint_as_float(b7 & 0xFFFF0000u);
  l.x = pack2hi(__float_as_uint(l0), __float_as_uint(l1));
  l.y = pack2hi(__float_as_uint(l2), __float_as_uint(l3));
  l.z = pack2hi(__float_as_uint(l4), __float_as_uint(l5));
  l.w = pack2hi(__float_as_uint(l6), __float_as_uint(l7));
}

// ------------------------------------------------- split-bf16 MFMA Gram
// grid: (32 chunks, 3 tile-pairs {(0,0),(0,1),(1,1)}, 9 mats: z=0..7 batch, z=8 target)
__global__ __launch_bounds__(256, 2)
void gram_mfma_kernel(const float* __restrict__ X, const float* __restrict__ TF,
                      float* __restrict__ srmB, float* __restrict__ srmT,
                      float* __restrict__ msumB, float* __restrict__ msumT) {
  __shared__ __align__(16) char ldsAh[16384];
  __shared__ __align__(16) char ldsAl[16384];
  __shared__ __align__(16) char ldsBh[16384];
  __shared__ __align__(16) char ldsBl[16384];

  const int pair = blockIdx.y;
  const int ti = (pair == 2) ? 1 : 0;
  const int tj = (pair == 0) ? 0 : 1;
  const bool diag = (ti == tj);
  const int b = blockIdx.z;

  const float* Xb; float* srm; float* msum; int K, kchunk;
  if (b == 8) { Xb = TF; srm = srmT; msum = msumT; K = 16384; kchunk = 512; }
  else {
    Xb = X + (size_t)b * 256 * 65536;
    srm = srmB + ((size_t)b << 16);
    msum = msumB + (b << 8);
    K = 65536; kchunk = 2048;
  }
  const float* __restrict__ Ab = Xb + (size_t)(ti * 128) * (size_t)K;
  const float* __restrict__ Bb = Xb + (size_t)(tj * 128) * (size_t)K;
  const int k0 = blockIdx.x * kchunk;

  const int t = threadIdx.x;
  const int lane = t & 63, wid = t >> 6;
  const int wr = (wid >> 1) * 64;
  const int wc = (wid & 1) * 64;
  const int srow = t >> 3;
  const int sspan = t & 7;

  f32x4 acc[4][4];
  #pragma unroll
  for (int m = 0; m < 4; ++m)
    #pragma unroll
    for (int n = 0; n < 4; ++n) acc[m][n] = (f32x4){0.f, 0.f, 0.f, 0.f};

  float rsum[4] = {0.f, 0.f, 0.f, 0.f};

  const float* pA = Ab + (size_t)srow * K + k0 + sspan * 8;
  const float* pB = Bb + (size_t)srow * K + k0 + sspan * 8;

  for (int kk = 0; kk < kchunk; kk += 64) {
    float4 ra[8], rb[8];
    #pragma unroll
    for (int rep = 0; rep < 4; ++rep) {
      const float* p = pA + (size_t)(rep * 32) * K + kk;
      ra[2 * rep]     = *(const float4*)(p);
      ra[2 * rep + 1] = *(const float4*)(p + 4);
    }
    if (!diag) {
      #pragma unroll
      for (int rep = 0; rep < 4; ++rep) {
        const float* p = pB + (size_t)(rep * 32) * K + kk;
        rb[2 * rep]     = *(const float4*)(p);
        rb[2 * rep + 1] = *(const float4*)(p + 4);
      }
    } else {
      #pragma unroll
      for (int rep = 0; rep < 4; ++rep) {
        float4 u0 = ra[2 * rep], u1 = ra[2 * rep + 1];
        rsum[rep] += (u0.x + u0.y) + (u0.z + u0.w) + (u1.x + u1.y) + (u1.z + u1.w);
      }
    }
    __syncthreads();
    #pragma unroll
    for (int rep = 0; rep < 4; ++rep) {
      int r = srow + rep * 32;
      int off = (r << 7) + ((sspan << 4) ^ ((r & 7) << 4));
      uint4 h, l;
      cvt_span(ra[2 * rep], ra[2 * rep + 1], h, l);
      *(uint4*)(ldsAh + off) = h;
      *(uint4*)(ldsAl + off) = l;
      if (!diag) {
        cvt_span(rb[2 * rep], rb[2 * rep + 1], h, l);
        *(uint4*)(ldsBh + off) = h;
        *(uint4*)(ldsBl + off) = l;
      }
    }
    __syncthreads();
    const char* BH = diag ? ldsAh : ldsBh;
    const char* BL = diag ? ldsAl : ldsBl;
    #pragma unroll
    for (int ks = 0; ks < 2; ++ks) {
      const int kb = ks * 64 + ((lane >> 4) << 4);
      bf16x8 ah[4], al[4];
      #pragma unroll
      for (int m = 0; m < 4; ++m) {
        int r = wr + m * 16 + (lane & 15);
        int o = (r << 7) + (kb ^ ((r & 7) << 4));
        ah[m] = *(const bf16x8*)(ldsAh + o);
        al[m] = *(const bf16x8*)(ldsAl + o);
      }
      #pragma unroll
      for (int n = 0; n < 4; ++n) {
        int r = wc + n * 16 + (lane & 15);
        int o = (r << 7) + (kb ^ ((r & 7) << 4));
        bf16x8 bh = *(const bf16x8*)(BH + o);
        bf16x8 bl = *(const bf16x8*)(BL + o);
        #pragma unroll
        for (int m = 0; m < 4; ++m) {
          acc[m][n] = __builtin_amdgcn_mfma_f32_16x16x32_bf16(ah[m], bh, acc[m][n], 0, 0, 0);
          acc[m][n] = __builtin_amdgcn_mfma_f32_16x16x32_bf16(ah[m], bl, acc[m][n], 0, 0, 0);
          acc[m][n] = __builtin_amdgcn_mfma_f32_16x16x32_bf16(al[m], bh, acc[m][n], 0, 0, 0);
        }
      }
    }
  }
  if (diag) {
    int rbase = ti * 128 + srow;
    #pragma unroll
    for (int rep = 0; rep < 4; ++rep)
      atomicAdd(msum + rbase + rep * 32, rsum[rep]);
  }
  const int rq = (lane >> 4) << 2;
  const int cl = lane & 15;
  #pragma unroll
  for (int m = 0; m < 4; ++m) {
    #pragma unroll
    for (int n = 0; n < 4; ++n) {
      #pragma unroll
      for (int q = 0; q < 4; ++q) {
        int r = ti * 128 + wr + m * 16 + rq + q;
        int c = tj * 128 + wc + n * 16 + cl;
        atomicAdd(srm + (size_t)r * 256 + c, acc[m][n][q]);
      }
    }
  }
}

// ------------------------------------------------- MFMA 256x256x256 tile GEMM
// C-tile(64x64, idx tl 0..15) of A@B, A row-major, B SYMMETRIC (staged from rows).
// Split-bf16 3-term. LDS: 4 x 8KB buffers passed in. acc result in regs.
__device__ __forceinline__ void mfma_gemm256_tile(
    const float* __restrict__ A, const float* __restrict__ B, int tl,
    char* ldsAh, char* ldsAl, char* ldsBh, char* ldsBl,
    f32x4 (&acc)[2][2]) {
  const int t = threadIdx.x;
  const int lane = t & 63, wid = t >> 6;
  const int tr = (tl >> 2) * 64, tc = (tl & 3) * 64;
  const int wr = (wid >> 1) * 32, wc = (wid & 1) * 32;
  const int srow = t >> 2, sspan = t & 3;

  #pragma unroll
  for (int m = 0; m < 2; ++m)
    #pragma unroll
    for (int n = 0; n < 2; ++n) acc[m][n] = (f32x4){0.f, 0.f, 0.f, 0.f};

  const float* pA = A + (size_t)(tr + srow) * 256 + sspan * 16;
  const float* pB = B + (size_t)(tc + srow) * 256 + sspan * 16;

  for (int k0 = 0; k0 < 256; k0 += 64) {
    float4 a0 = *(const float4*)(pA + k0);
    float4 a1 = *(const float4*)(pA + k0 + 4);
    float4 a2 = *(const float4*)(pA + k0 + 8);
    float4 a3 = *(const float4*)(pA + k0 + 12);
    float4 b0 = *(const float4*)(pB + k0);
    float4 b1 = *(const float4*)(pB + k0 + 4);
    float4 b2 = *(const float4*)(pB + k0 + 8);
    float4 b3 = *(const float4*)(pB + k0 + 12);
    __syncthreads();
    {
      int base = srow << 7;
      int sw = (srow & 7) << 4;
      int kb0 = (sspan * 32) ^ sw, kb1 = (sspan * 32 + 16) ^ sw;
      uint4 h, l;
      cvt_span(a0, a1, h, l);
      *(uint4*)(ldsAh + base + kb0) = h; *(uint4*)(ldsAl + base + kb0) = l;
      cvt_span(a2, a3, h, l);
      *(uint4*)(ldsAh + base + kb1) = h; *(uint4*)(ldsAl + base + kb1) = l;
      cvt_span(b0, b1, h, l);
      *(uint4*)(ldsBh + base + kb0) = h; *(uint4*)(ldsBl + base + kb0) = l;
      cvt_span(b2, b3, h, l);
      *(uint4*)(ldsBh + base + kb1) = h; *(uint4*)(ldsBl + base + kb1) = l;
    }
    __syncthreads();
    #pragma unroll
    for (int ks = 0; ks < 2; ++ks) {
      const int kb = ks * 64 + ((lane >> 4) << 4);
      bf16x8 ah[2], al[2];
      #pragma unroll
      for (int m = 0; m < 2; ++m) {
        int r = wr + m * 16 + (lane & 15);
        int o = (r << 7) + (kb ^ ((r & 7) << 4));
        ah[m] = *(const bf16x8*)(ldsAh + o);
        al[m] = *(const bf16x8*)(ldsAl + o);
      }
      #pragma unroll
      for (int n = 0; n < 2; ++n) {
        int r = wc + n * 16 + (lane & 15);
        int o = (r << 7) + (kb ^ ((r & 7) << 4));
        bf16x8 bh = *(const bf16x8*)(ldsBh + o);
        bf16x8 bl = *(const bf16x8*)(ldsBl + o);
        #pragma unroll
        for (int m = 0; m < 2; ++m) {
          acc[m][n] = __builtin_amdgcn_mfma_f32_16x16x32_bf16(ah[m], bh, acc[m][n], 0, 0, 0);
          acc[m][n] = __builtin_amdgcn_mfma_f32_16x16x32_bf16(ah[m], bl, acc[m][n], 0, 0, 0);
          acc[m][n] = __builtin_amdgcn_mfma_f32_16x16x32_bf16(al[m], bh, acc[m][n], 0, 0, 0);
        }
      }
    }
  }
}

// output coords for the tile epilogues (m89 C/D layout)
#define TILE_RC(tl, wid, lane, m, n, q, r, c) \
  int r = ((tl) >> 2) * 64 + (((wid) >> 1) * 32) + (m) * 16 + (((lane) >> 4) << 2) + (q); \
  int c = ((tl) & 3) * 64 + (((wid) & 1) * 32) + (n) * 16 + ((lane) & 15);

// ------------------------------------------------- target NS chain (coop, 128 blocks)
__global__ __launch_bounds__(256, 2)
void ns_coop_target(const float* __restrict__ srm, const float* __restrict__ msum,
                    float* __restrict__ cov, float* __restrict__ covSqrt,
                    float* __restrict__ Ya, float* __restrict__ Za,
                    float* __restrict__ Yb, float* __restrict__ Zb,
                    float* __restrict__ Wb, float* __restrict__ ssq) {
  __shared__ __align__(16) char ldsAh[8192];
  __shared__ __align__(16) char ldsAl[8192];
  __shared__ __align__(16) char ldsBh[8192];
  __shared__ __align__(16) char ldsBl[8192];
  cg::grid_group g = cg::this_grid();
  const int bid = blockIdx.x, tid = threadIdx.x;
  const int lane = tid & 63, wid = tid >> 6;
  const int gt = bid * 256 + tid;             // 0..32767
  const float inv_n = 1.f / 16384.f;
  f32x4 acc[2][2];

  // phase 0: cov (mirror) + Frobenius
  float fs = 0.f;
  for (int i = gt; i < 65536; i += 32768) {
    int c = i >> 8, d = i & 255;
    float s = ((c >> 7) > (d >> 7)) ? srm[(d << 8) + c] : srm[i];
    float v = s * inv_n - (msum[c] * inv_n) * (msum[d] * inv_n);
    if (c == d) v += STYLE_EPS;
    cov[i] = v;
    fs = fmaf(v, v, fs);
  }
  fs = block_reduce_sum(fs);
  if (tid == 0) atomicAdd(ssq, fs);
  g.sync();

  // phase 1 (init + iter1): Y1 = 1.5 rn cov - 0.5 rn^2 cov@cov ; Z1 = 1.5I - 0.5 rn cov
  float rn = rsqrtf(ssq[0]);
  if (bid < 16) {
    mfma_gemm256_tile(cov, cov, bid, ldsAh, ldsAl, ldsBh, ldsBl, acc);
    #pragma unroll
    for (int m = 0; m < 2; ++m)
      #pragma unroll
      for (int n = 0; n < 2; ++n)
        #pragma unroll
        for (int q = 0; q < 4; ++q) {
          TILE_RC(bid, wid, lane, m, n, q, r, c)
          size_t idx = (size_t)r * 256 + c;
          Ya[idx] = 1.5f * rn * cov[idx] - 0.5f * rn * rn * acc[m][n][q];
        }
  } else {
    int li = (bid - 16) * 256 + tid;          // 112 blocks
    for (int i = li; i < 65536; i += 28672) {
      float v = -0.5f * rn * cov[i];
      if ((i >> 8) == (i & 255)) v += 1.5f;
      Za[i] = v;
    }
  }
  g.sync();

  // iterations 2..12 (11 iters): W = Z@Y ; Yn = 1.5Y-0.5 W@Y ; Zn = 1.5Z-0.5 W@Z
  float *y = Ya, *z = Za, *yn = Yb, *zn = Zb;
  for (int it = 0; it < 11; ++it) {
    if (bid < 16) {
      mfma_gemm256_tile(z, y, bid, ldsAh, ldsAl, ldsBh, ldsBl, acc);
      #pragma unroll
      for (int m = 0; m < 2; ++m)
        #pragma unroll
        for (int n = 0; n < 2; ++n)
          #pragma unroll
          for (int q = 0; q < 4; ++q) {
            TILE_RC(bid, wid, lane, m, n, q, r, c)
            Wb[(size_t)r * 256 + c] = acc[m][n][q];
          }
    }
    g.sync();
    if (bid < 32) {
      const float* Bp = (bid < 16) ? y : z;
      float* Cp = (bid < 16) ? yn : zn;
      int tl = bid & 15;
      mfma_gemm256_tile(Wb, Bp, tl, ldsAh, ldsAl, ldsBh, ldsBl, acc);
      #pragma unroll
      for (int m = 0; m < 2; ++m)
        #pragma unroll
        for (int n = 0; n < 2; ++n)
          #pragma unroll
          for (int q = 0; q < 4; ++q) {
            TILE_RC(tl, wid, lane, m, n, q, r, c)
            size_t idx = (size_t)r * 256 + c;
            Cp[idx] = 1.5f * Bp[idx] - 0.5f * acc[m][n][q];
          }
    }
    g.sync();
    float* tp;
    tp = y; y = yn; yn = tp;
    tp = z; z = zn; zn = tp;
  }
  // final: covSqrt = y * ssq^(1/4)
  float f = sqrtf(sqrtf(ssq[0]));
  for (int i = gt; i < 65536; i += 32768) covSqrt[i] = y[i] * f;
}

// ------------------------------------------------- batch chain (coop, 256 blocks)
__global__ __launch_bounds__(256, 2)
void ns_coop_batch(const float* __restrict__ srm, const float* __restrict__ msumB,
                   const float* __restrict__ msumT,
                   const float* __restrict__ covTs, const float* __restrict__ covT,
                   float* __restrict__ covB, float* __restrict__ P1, float* __restrict__ Mm,
                   float* __restrict__ Ya, float* __restrict__ Za,
                   float* __restrict__ Yb, float* __restrict__ Zb,
                   float* __restrict__ Wb, float* __restrict__ ssq,
                   float* __restrict__ out) {
  __shared__ __align__(16) char ldsAh[8192];
  __shared__ __align__(16) char ldsAl[8192];
  __shared__ __align__(16) char ldsBh[8192];
  __shared__ __align__(16) char ldsBl[8192];
  cg::grid_group g = cg::this_grid();
  const int bid = blockIdx.x, tid = threadIdx.x;
  const int lane = tid & 63, wid = tid >> 6;
  const int gt = bid * 256 + tid;              // 0..65535
  const float inv_n = 1.f / 65536.f;
  const size_t M = 65536;
  f32x4 acc[2][2];

  // phase 0: covB finalize (mirror)
  for (int i = gt; i < 524288; i += 65536) {
    int m = i >> 16, r = i & 65535;
    int c = r >> 8, d = r & 255;
    size_t base = (size_t)m << 16;
    float s = ((c >> 7) > (d >> 7)) ? srm[base + ((size_t)d << 8) + c] : srm[i];
    float mc = msumB[(m << 8) + c] * inv_n, md = msumB[(m << 8) + d] * inv_n;
    float v = s * inv_n - mc * md;
    if (c == d) v += STYLE_EPS;
    covB[i] = v;
  }
  g.sync();

  // phase 1: P1 = covTs @ covB   (B = covB symmetric)
  if (bid < 128) {
    int m = bid >> 4, tl = bid & 15;
    mfma_gemm256_tile(covTs, covB + m * M, tl, ldsAh, ldsAl, ldsBh, ldsBl, acc);
    float* Cp = P1 + m * M;
    #pragma unroll
    for (int mi = 0; mi < 2; ++mi)
      #pragma unroll
      for (int n = 0; n < 2; ++n)
        #pragma unroll
        for (int q = 0; q < 4; ++q) {
          TILE_RC(tl, wid, lane, mi, n, q, r, c)
          Cp[(size_t)r * 256 + c] = acc[mi][n][q];
        }
  }
  g.sync();

  // phase 2: Mm = P1 @ covTs  (+ frob)
  if (bid < 128) {
    int m = bid >> 4, tl = bid & 15;
    mfma_gemm256_tile(P1 + m * M, covTs, tl, ldsAh, ldsAl, ldsBh, ldsBl, acc);
    float* Cp = Mm + m * M;
    float fs = 0.f;
    #pragma unroll
    for (int mi = 0; mi < 2; ++mi)
      #pragma unroll
      for (int n = 0; n < 2; ++n)
        #pragma unroll
        for (int q = 0; q < 4; ++q) {
          TILE_RC(tl, wid, lane, mi, n, q, r, c)
          float v = acc[mi][n][q];
          Cp[(size_t)r * 256 + c] = v;
          fs = fmaf(v, v, fs);
        }
    fs = block_reduce_sum(fs);
    if (tid == 0) atomicAdd(ssq + m, fs);
  }
  g.sync();

  // phase 3 (init + iter1): Y1 = 1.5 rn Mm - 0.5 rn^2 Mm@Mm ; Z1 = 1.5I - 0.5 rn Mm
  if (bid < 128) {
    int m = bid >> 4, tl = bid & 15;
    float rn = rsqrtf(ssq[m]);
    const float* Ap = Mm + m * M;
    mfma_gemm256_tile(Ap, Ap, tl, ldsAh, ldsAl, ldsBh, ldsBl, acc);
    float* Cp = Ya + m * M;
    #pragma unroll
    for (int mi = 0; mi < 2; ++mi)
      #pragma unroll
      for (int n = 0; n < 2; ++n)
        #pragma unroll
        for (int q = 0; q < 4; ++q) {
          TILE_RC(tl, wid, lane, mi, n, q, r, c)
          size_t idx = (size_t)r * 256 + c;
          Cp[idx] = 1.5f * rn * Ap[idx] - 0.5f * rn * rn * acc[mi][n][q];
        }
  } else {
    int li = (bid - 128) * 256 + tid;          // 0..32767
    for (int i = li; i < 524288; i += 32768) {
      int m = i >> 16, r = i & 65535;
      float rn = rsqrtf(ssq[m]);
      float v = -0.5f * rn * Mm[i];
      if ((r >> 8) == (r & 255)) v += 1.5f;
      Za[i] = v;
    }
  }
  g.sync();

  // iterations 2..12 (11 iters)
  float *y = Ya, *z = Za, *yn = Yb, *zn = Zb;
  for (int it = 0; it < 11; ++it) {
    if (bid < 128) {
      int m = bid >> 4, tl = bid & 15;
      mfma_gemm256_tile(z + m * M, y + m * M, tl, ldsAh, ldsAl, ldsBh, ldsBl, acc);
      float* Cp = Wb + m * M;
      #pragma unroll
      for (int mi = 0; mi < 2; ++mi)
        #pragma unroll
        for (int n = 0; n < 2; ++n)
          #pragma unroll
          for (int q = 0; q < 4; ++q) {
            TILE_RC(tl, wid, lane, mi, n, q, r, c)
            Cp[(size_t)r * 256 + c] = acc[mi][n][q];
          }
    }
    g.sync();
    {
      int m = (bid & 127) >> 4, tl = bid & 15;
      const float* Bp = (bid < 128) ? (y + m * M) : (z + m * M);
      float* Cp = (bid < 128) ? (yn + m * M) : (zn + m * M);
      mfma_gemm256_tile(Wb + m * M, Bp, tl, ldsAh, ldsAl, ldsBh, ldsBl, acc);
      #pragma unroll
      for (int mi = 0; mi < 2; ++mi)
        #pragma unroll
        for (int n = 0; n < 2; ++n)
          #pragma unroll
          for (int q = 0; q < 4; ++q) {
            TILE_RC(tl, wid, lane, mi, n, q, r, c)
            size_t idx = (size_t)r * 256 + c;
            Cp[idx] = 1.5f * Bp[idx] - 0.5f * acc[mi][n][q];
          }
    }
    g.sync();
    float* tp;
    tp = y; y = yn; yn = tp;
    tp = z; z = zn; zn = tp;
  }

  // loss (block 0)
  if (bid == 0) {
    const float invT = 1.f / 16384.f;
    float s1 = 0.f, s2 = 0.f;
    for (int i = tid; i < 2048; i += 256) {
      int b = i >> 8, c = i & 255;
      float dm = msumB[i] * inv_n - msumT[c] * invT;
      s1 += dm * dm;
      size_t di = ((size_t)b << 16) + (size_t)c * 257;
      float fb = sqrtf(sqrtf(ssq[b]));
      s2 += covT[(size_t)c * 257] + covB[di] - 2.f * fb * y[di];
    }
    s1 = block_reduce_sum(s1);
    s2 = block_reduce_sum(s2);
    if (tid == 0) out[0] = (s1 + s2) / 2048.f;
  }
}

// ------------------------------------------------------------------- launch
extern "C" void kernel_launch(void* const* d_in, const int* in_sizes, int n_in,
                              void* d_out, int out_size, void* d_ws, size_t ws_size,
                              hipStream_t stream) {
  const float* x  = (const float*)d_in[0];   // [8,256,256,256]
  const float* tf = (const float*)d_in[1];   // [256,16384]
  float* out = (float*)d_out;
  float* W = (float*)d_ws;

  const size_t M = 65536;   // 256*256
  float* sumsq = W;                       // 16  (batch 0..7, target at 8)
  float* meanT = W + 16;                  // 256  (raw row sums)
  float* meanB = meanT + 256;             // 2048 (raw row sums)
  float* srmT  = meanB + 2048;            // 65536
  float* srmB  = srmT + M;                // 8*65536
  float* covT  = srmB + 8 * M;            // 65536
  float* covTs = covT + M;                // 65536
  float* covB  = covTs + M;               // 8*65536
  float* P1    = covB + 8 * M;            // 8*65536
  float* Mm    = P1 + 8 * M;              // 8*65536
  float* Ya    = Mm + 8 * M;              // 8*65536
  float* Yb    = Ya + 8 * M;
  float* Za    = Yb + 8 * M;
  float* Zb    = Za + 8 * M;
  float* Wm    = Zb + 8 * M;              // W = Z@Y scratch

  // zero atomic accumulators: sumsq + mean sums + srmT + srmB (contiguous)
  hipMemsetAsync(W, 0, (16 + 256 + 2048 + 9 * M) * sizeof(float), stream);

  // grams (z=0..7 batch mats, z=8 target) + fused row-sum accumulation
  gram_mfma_kernel<<<dim3(32, 3, 9), 256, 0, stream>>>(x, tf, srmB, srmT, meanB, meanT);

  // target chain: covT -> NS -> covTs
  {
    float* ssqT = sumsq + 8;
    void* args[] = {(void*)&srmT, (void*)&meanT, (void*)&covT, (void*)&covTs,
                    (void*)&Ya, (void*)&Za, (void*)&Yb, (void*)&Zb, (void*)&Wm,
                    (void*)&ssqT};
    hipLaunchCooperativeKernel((void*)ns_coop_target, dim3(128), dim3(256), args, 0, stream);
  }

  // batch chain: covB -> sandwich -> NS(8) -> loss
  {
    void* args[] = {(void*)&srmB, (void*)&meanB, (void*)&meanT, (void*)&covTs, (void*)&covT,
                    (void*)&covB, (void*)&P1, (void*)&Mm,
                    (void*)&Ya, (void*)&Za, (void*)&Yb, (void*)&Zb, (void*)&Wm,
                    (void*)&sumsq, (void*)&out};
    hipLaunchCooperativeKernel((void*)ns_coop_batch, dim3(256), dim3(256), args, 0, stream);
  }
}